// Round 1
// baseline (1418.311 us; speedup 1.0000x reference)
//
#include <hip/hip_runtime.h>
#include <hip/hip_bf16.h>
#include <stdint.h>

// ExpHashEncoder: blended multiresolution hash-grid encode.
//   inputs:  (524288, 3) f32
//   exp:     (4, 8) f32
//   embeddings_mean: (1, 7131219, 2) f32
//   embeddings:      (7, 7131219, 2) f32
//   xyzstorays: (524288,) i32  -> frame = v >> 10
//   out: (524288, 32) f32
//
// Strategy: pass A blends the 8 basis tables into a per-frame table cur[4][T][2]
// in d_ws (streaming, ~684 MB traffic). Pass B does the trilinear hash gather
// from cur (random 8B gathers, table ~L3-resident). Tiered on ws_size:
// fp32 table (228 MB) -> bf16 table (114 MB) -> fused fallback (no ws).

static constexpr int    NPOINTS = 524288;
static constexpr int    NLEV    = 16;
static constexpr size_t TOTAL_T = 7131219;   // sum of per-level param counts

#define OFFS_INIT {0u,4913u,40850u,315475u,839763u,1364051u,1888339u,2412627u, \
                   2936915u,3461203u,3985491u,4509779u,5034067u,5558355u,6082643u,6606931u}

// ---------------------------------------------------------------- blend (fp32)
__global__ __launch_bounds__(256) void blend_f32_kernel(
    const float2* __restrict__ mean, const float2* __restrict__ emb,
    const float* __restrict__ expw, float2* __restrict__ cur)
{
    size_t t = (size_t)blockIdx.x * 256 + threadIdx.x;
    if (t >= TOTAL_T) return;
    float2 m = mean[t];
    float2 o0, o1, o2, o3;
    float s;
    s = expw[0];  o0.x = s * m.x; o0.y = s * m.y;
    s = expw[8];  o1.x = s * m.x; o1.y = s * m.y;
    s = expw[16]; o2.x = s * m.x; o2.y = s * m.y;
    s = expw[24]; o3.x = s * m.x; o3.y = s * m.y;
#pragma unroll
    for (int b = 0; b < 7; ++b) {
        float2 e = emb[(size_t)b * TOTAL_T + t];
        s = expw[1 + b];  o0.x = fmaf(s, e.x, o0.x); o0.y = fmaf(s, e.y, o0.y);
        s = expw[9 + b];  o1.x = fmaf(s, e.x, o1.x); o1.y = fmaf(s, e.y, o1.y);
        s = expw[17 + b]; o2.x = fmaf(s, e.x, o2.x); o2.y = fmaf(s, e.y, o2.y);
        s = expw[25 + b]; o3.x = fmaf(s, e.x, o3.x); o3.y = fmaf(s, e.y, o3.y);
    }
    cur[t]               = o0;
    cur[TOTAL_T + t]     = o1;
    cur[2 * TOTAL_T + t] = o2;
    cur[3 * TOTAL_T + t] = o3;
}

// ---------------------------------------------------------------- blend (bf16)
__global__ __launch_bounds__(256) void blend_bf16_kernel(
    const float2* __restrict__ mean, const float2* __restrict__ emb,
    const float* __restrict__ expw, __hip_bfloat162* __restrict__ cur)
{
    size_t t = (size_t)blockIdx.x * 256 + threadIdx.x;
    if (t >= TOTAL_T) return;
    float2 m = mean[t];
    float2 o[4];
#pragma unroll
    for (int f = 0; f < 4; ++f) {
        float s = expw[8 * f];
        o[f].x = s * m.x; o[f].y = s * m.y;
    }
#pragma unroll
    for (int b = 0; b < 7; ++b) {
        float2 e = emb[(size_t)b * TOTAL_T + t];
#pragma unroll
        for (int f = 0; f < 4; ++f) {
            float s = expw[8 * f + 1 + b];
            o[f].x = fmaf(s, e.x, o[f].x); o[f].y = fmaf(s, e.y, o[f].y);
        }
    }
#pragma unroll
    for (int f = 0; f < 4; ++f) {
        __hip_bfloat162 r;
        r.x = __float2bfloat16(o[f].x);
        r.y = __float2bfloat16(o[f].y);
        cur[(size_t)f * TOTAL_T + t] = r;
    }
}

// ---------------------------------------------------------------- gather
__device__ __forceinline__ float2 tab_load(const float2* __restrict__ t, uint32_t i) {
    return t[i];
}
__device__ __forceinline__ float2 tab_load(const __hip_bfloat162* __restrict__ t, uint32_t i) {
    __hip_bfloat162 v = t[i];
    return make_float2(__bfloat162float(v.x), __bfloat162float(v.y));
}

template <typename TAB>
__global__ __launch_bounds__(256) void gather_kernel(
    const float* __restrict__ xyz, const int* __restrict__ rays,
    const TAB* __restrict__ cur, float* __restrict__ out)
{
    int p = blockIdx.x * 256 + threadIdx.x;
    if (p >= NPOINTS) return;
    float x = xyz[3 * p], y = xyz[3 * p + 1], z = xyz[3 * p + 2];
    int frame = rays[p] >> 10;
    const TAB* __restrict__ tab = cur + (size_t)frame * TOTAL_T;

    constexpr uint32_t OFFS[16] = OFFS_INIT;
    float acc[2 * NLEV];

#pragma unroll
    for (int l = 0; l < NLEV; ++l) {
        float scale = (float)((16 << l) - 1);
        float px = fmaf(x, scale, 0.5f);
        float py = fmaf(y, scale, 0.5f);
        float pz = fmaf(z, scale, 0.5f);
        float fx = floorf(px), fy = floorf(py), fz = floorf(pz);
        float wx = px - fx, wy = py - fy, wz = pz - fz;
        int ix = (int)fx, iy = (int)fy, iz = (int)fz;
        uint32_t base = OFFS[l];
        float sx = 0.f, sy = 0.f;
#pragma unroll
        for (int c = 0; c < 8; ++c) {
            int bx = (c >> 2) & 1, by = (c >> 1) & 1, bz = c & 1;
            uint32_t idx;
            if (l < 3) {
                uint32_t st = (l == 0) ? 17u : (l == 1) ? 33u : 65u;
                idx = (uint32_t)(ix + bx) + (uint32_t)(iy + by) * st
                    + (uint32_t)(iz + bz) * st * st;
            } else {
                idx = ((uint32_t)(ix + bx)
                     ^ ((uint32_t)(iy + by) * 2654435761u)
                     ^ ((uint32_t)(iz + bz) * 805459861u)) & 0x7FFFFu;
            }
            float w = (bx ? wx : 1.f - wx) * (by ? wy : 1.f - wy) * (bz ? wz : 1.f - wz);
            float2 v = tab_load(tab, base + idx);
            sx = fmaf(w, v.x, sx);
            sy = fmaf(w, v.y, sy);
        }
        acc[2 * l]     = sx;
        acc[2 * l + 1] = sy;
    }

    float4* o4 = (float4*)(out + (size_t)p * 32);
#pragma unroll
    for (int i = 0; i < 8; ++i)
        o4[i] = make_float4(acc[4 * i], acc[4 * i + 1], acc[4 * i + 2], acc[4 * i + 3]);
}

// ------------------------------------------------- fused fallback (tiny ws)
__global__ __launch_bounds__(256) void fused_fallback_kernel(
    const float* __restrict__ xyz, const int* __restrict__ rays,
    const float* __restrict__ expw,
    const float2* __restrict__ mean, const float2* __restrict__ emb,
    float* __restrict__ out)
{
    int p = blockIdx.x * 256 + threadIdx.x;
    if (p >= NPOINTS) return;
    float x = xyz[3 * p], y = xyz[3 * p + 1], z = xyz[3 * p + 2];
    int frame = rays[p] >> 10;
    float e[8];
#pragma unroll
    for (int b = 0; b < 8; ++b) e[b] = expw[8 * frame + b];

    constexpr uint32_t OFFS[16] = OFFS_INIT;

    for (int l = 0; l < NLEV; ++l) {
        float scale = (float)((16 << l) - 1);
        float px = fmaf(x, scale, 0.5f);
        float py = fmaf(y, scale, 0.5f);
        float pz = fmaf(z, scale, 0.5f);
        float fx = floorf(px), fy = floorf(py), fz = floorf(pz);
        float wx = px - fx, wy = py - fy, wz = pz - fz;
        int ix = (int)fx, iy = (int)fy, iz = (int)fz;
        uint32_t base = OFFS[l];
        float sx = 0.f, sy = 0.f;
#pragma unroll
        for (int c = 0; c < 8; ++c) {
            int bx = (c >> 2) & 1, by = (c >> 1) & 1, bz = c & 1;
            uint32_t idx;
            if (l < 3) {
                uint32_t st = (l == 0) ? 17u : (l == 1) ? 33u : 65u;
                idx = (uint32_t)(ix + bx) + (uint32_t)(iy + by) * st
                    + (uint32_t)(iz + bz) * st * st;
            } else {
                idx = ((uint32_t)(ix + bx)
                     ^ ((uint32_t)(iy + by) * 2654435761u)
                     ^ ((uint32_t)(iz + bz) * 805459861u)) & 0x7FFFFu;
            }
            uint32_t g = base + idx;
            float2 m = mean[g];
            float vx = e[0] * m.x, vy = e[0] * m.y;
#pragma unroll
            for (int b = 0; b < 7; ++b) {
                float2 t = emb[(size_t)b * TOTAL_T + g];
                vx = fmaf(e[1 + b], t.x, vx);
                vy = fmaf(e[1 + b], t.y, vy);
            }
            float w = (bx ? wx : 1.f - wx) * (by ? wy : 1.f - wy) * (bz ? wz : 1.f - wz);
            sx = fmaf(w, vx, sx);
            sy = fmaf(w, vy, sy);
        }
        out[(size_t)p * 32 + 2 * l]     = sx;
        out[(size_t)p * 32 + 2 * l + 1] = sy;
    }
}

// ---------------------------------------------------------------- launch
extern "C" void kernel_launch(void* const* d_in, const int* in_sizes, int n_in,
                              void* d_out, int out_size, void* d_ws, size_t ws_size,
                              hipStream_t stream) {
    const float* inputs = (const float*)d_in[0];     // (524288,3)
    const float* expw   = (const float*)d_in[1];     // (4,8)
    const float* mean   = (const float*)d_in[2];     // (1,T,2)
    const float* emb    = (const float*)d_in[3];     // (7,T,2)
    const int*   rays   = (const int*)d_in[4];       // (524288,)
    float* out = (float*)d_out;

    const int blend_blocks  = (int)((TOTAL_T + 255) / 256);
    const int gather_blocks = NPOINTS / 256;

    const size_t need_f32  = (size_t)4 * TOTAL_T * sizeof(float2);          // 228.2 MB
    const size_t need_bf16 = (size_t)4 * TOTAL_T * sizeof(__hip_bfloat162); // 114.1 MB

    if (ws_size >= need_f32) {
        float2* cur = (float2*)d_ws;
        blend_f32_kernel<<<blend_blocks, 256, 0, stream>>>(
            (const float2*)mean, (const float2*)emb, expw, cur);
        gather_kernel<float2><<<gather_blocks, 256, 0, stream>>>(
            inputs, rays, cur, out);
    } else if (ws_size >= need_bf16) {
        __hip_bfloat162* cur = (__hip_bfloat162*)d_ws;
        blend_bf16_kernel<<<blend_blocks, 256, 0, stream>>>(
            (const float2*)mean, (const float2*)emb, expw, cur);
        gather_kernel<__hip_bfloat162><<<gather_blocks, 256, 0, stream>>>(
            inputs, rays, cur, out);
    } else {
        fused_fallback_kernel<<<gather_blocks, 256, 0, stream>>>(
            inputs, rays, expw, (const float2*)mean, (const float2*)emb, out);
    }
}

// Round 3
// 1124.146 us; speedup vs baseline: 1.2617x; 1.2617x over previous
//
#include <hip/hip_runtime.h>
#include <hip/hip_bf16.h>
#include <stdint.h>

// ExpHashEncoder v2b.
// Pass A: blend 8 basis tables -> per-frame bf16 table in d_ws (stride TPAD,
//         padded so every frame base is 256B-aligned; 4 entries/thread, uint4
//         stores, non-temporal basis reads to keep cur L3-resident).
// Pass B: level-phased gather. Grid phase p: phase 0 = dense levels 0-2
//         (5 MB working set), phases 1..13 = hash level p+2 (8 MB working set
//         across 4 frames -> ~50% per-XCD L2 residency vs ~4% monolithic).

static constexpr int      NPOINTS = 524288;
static constexpr size_t   TOTAL_T = 7131219;     // sum of per-level param counts
static constexpr uint32_t TPAD    = 7131264;     // TOTAL_T rounded up to 64
static constexpr size_t   NG4     = TOTAL_T / 4; // 1782804 full 4-entry groups

#define OFFS_INIT {0u,4913u,40850u,315475u,839763u,1364051u,1888339u,2412627u, \
                   2936915u,3461203u,3985491u,4509779u,5034067u,5558355u,6082643u,6606931u}

__device__ __forceinline__ uint32_t pack_bf16x2(float a, float b) {
    __hip_bfloat162 h;
    h.x = __float2bfloat16(a);
    h.y = __float2bfloat16(b);
    uint32_t u;
    __builtin_memcpy(&u, &h, 4);
    return u;
}

__device__ __forceinline__ float2 unpack_bf16x2(uint32_t u) {
    float2 r;
    uint32_t lx = u << 16;
    uint32_t ly = u & 0xFFFF0000u;
    __builtin_memcpy(&r.x, &lx, 4);
    __builtin_memcpy(&r.y, &ly, 4);
    return r;
}

__device__ __forceinline__ float2 nt_load_f2(const float2* p) {
    uint64_t raw = __builtin_nontemporal_load((const uint64_t*)p);
    float2 r;
    __builtin_memcpy(&r, &raw, 8);
    return r;
}

// ---------------------------------------------------------------- blend
__global__ __launch_bounds__(256) void blend_bf16x4_kernel(
    const float2* __restrict__ mean2, const float2* __restrict__ emb2,
    const float* __restrict__ expw, uint32_t* __restrict__ cur)
{
    size_t t = (size_t)blockIdx.x * 256 + threadIdx.x;
    if (t > NG4) return;

    if (t < NG4) {
        float ox[4][4], oy[4][4];   // [frame][entry-in-group]
#pragma unroll
        for (int k = 0; k < 4; ++k) {
            float2 m = nt_load_f2(&mean2[4 * t + k]);
#pragma unroll
            for (int f = 0; f < 4; ++f) {
                float s = expw[8 * f];
                ox[f][k] = s * m.x;
                oy[f][k] = s * m.y;
            }
        }
#pragma unroll
        for (int b = 0; b < 7; ++b) {
            const float2* __restrict__ eb = emb2 + (size_t)b * TOTAL_T;
#pragma unroll
            for (int k = 0; k < 4; ++k) {
                float2 e = nt_load_f2(&eb[4 * t + k]);
#pragma unroll
                for (int f = 0; f < 4; ++f) {
                    float s = expw[8 * f + 1 + b];
                    ox[f][k] = fmaf(s, e.x, ox[f][k]);
                    oy[f][k] = fmaf(s, e.y, oy[f][k]);
                }
            }
        }
#pragma unroll
        for (int f = 0; f < 4; ++f) {
            uint4 u;
            u.x = pack_bf16x2(ox[f][0], oy[f][0]);
            u.y = pack_bf16x2(ox[f][1], oy[f][1]);
            u.z = pack_bf16x2(ox[f][2], oy[f][2]);
            u.w = pack_bf16x2(ox[f][3], oy[f][3]);
            *(uint4*)(cur + (size_t)f * TPAD + 4 * t) = u;  // 16B-aligned: TPAD%64==0
        }
    } else {
        // tail: entries 4*NG4 .. TOTAL_T-1 (3 entries)
#pragma unroll
        for (int e4 = 0; e4 < 3; ++e4) {
            size_t e = 4 * NG4 + e4;
            float2 m = mean2[e];
            float vx[4], vy[4];
#pragma unroll
            for (int f = 0; f < 4; ++f) {
                float s = expw[8 * f];
                vx[f] = s * m.x; vy[f] = s * m.y;
            }
#pragma unroll
            for (int b = 0; b < 7; ++b) {
                float2 ev = emb2[(size_t)b * TOTAL_T + e];
#pragma unroll
                for (int f = 0; f < 4; ++f) {
                    float s = expw[8 * f + 1 + b];
                    vx[f] = fmaf(s, ev.x, vx[f]);
                    vy[f] = fmaf(s, ev.y, vy[f]);
                }
            }
#pragma unroll
            for (int f = 0; f < 4; ++f)
                cur[(size_t)f * TPAD + e] = pack_bf16x2(vx[f], vy[f]);
        }
    }
}

// ---------------------------------------------------------------- gather
// grid = 14 phases * 2048 point-blocks; phase = blockIdx.x>>11 (dispatch order
// sweeps phases sequentially so concurrent blocks share one level's table).
__global__ __launch_bounds__(256) void gather_lvl_kernel(
    const float* __restrict__ xyz, const int* __restrict__ rays,
    const uint32_t* __restrict__ cur, float* __restrict__ out)
{
    uint32_t phase = blockIdx.x >> 11;
    uint32_t pb    = blockIdx.x & 2047u;
    uint32_t p     = pb * 256u + threadIdx.x;   // 2048*256 == NPOINTS exactly

    float x = xyz[3 * p + 0], y = xyz[3 * p + 1], z = xyz[3 * p + 2];
    uint32_t frame = ((uint32_t)rays[p]) >> 10;
    const uint32_t* __restrict__ tab = cur + (size_t)frame * TPAD;

    if (phase == 0) {
        // dense levels 0..2
        float o[6];
        const uint32_t ST[3]  = {17u, 33u, 65u};
        const uint32_t OFF[3] = {0u, 4913u, 40850u};
#pragma unroll
        for (int l = 0; l < 3; ++l) {
            float scale = (float)((16 << l) - 1);
            float px = fmaf(x, scale, 0.5f);
            float py = fmaf(y, scale, 0.5f);
            float pz = fmaf(z, scale, 0.5f);
            float fx = floorf(px), fy = floorf(py), fz = floorf(pz);
            float wx = px - fx, wy = py - fy, wz = pz - fz;
            uint32_t ix = (uint32_t)(int)fx, iy = (uint32_t)(int)fy, iz = (uint32_t)(int)fz;
            uint32_t st = ST[l], st2 = st * st, base = OFF[l];
            float sx = 0.f, sy = 0.f;
#pragma unroll
            for (int c = 0; c < 8; ++c) {
                uint32_t bx = (c >> 2) & 1, by = (c >> 1) & 1, bz = c & 1;
                uint32_t idx = base + (ix + bx) + (iy + by) * st + (iz + bz) * st2;
                float w = (bx ? wx : 1.f - wx) * (by ? wy : 1.f - wy) * (bz ? wz : 1.f - wz);
                float2 v = unpack_bf16x2(tab[idx]);
                sx = fmaf(w, v.x, sx);
                sy = fmaf(w, v.y, sy);
            }
            o[2 * l] = sx; o[2 * l + 1] = sy;
        }
        float* ob = out + (size_t)p * 32;
        *(float4*)ob       = make_float4(o[0], o[1], o[2], o[3]);
        *(float2*)(ob + 4) = make_float2(o[4], o[5]);
    } else {
        // hash level l = phase + 2
        int l = (int)phase + 2;
        float scale = (float)((16 << l) - 1);
        uint32_t base = 315475u + ((phase - 1u) << 19);
        float px = fmaf(x, scale, 0.5f);
        float py = fmaf(y, scale, 0.5f);
        float pz = fmaf(z, scale, 0.5f);
        float fx = floorf(px), fy = floorf(py), fz = floorf(pz);
        float wx = px - fx, wy = py - fy, wz = pz - fz;
        uint32_t ix = (uint32_t)(int)fx, iy = (uint32_t)(int)fy, iz = (uint32_t)(int)fz;
        float sx = 0.f, sy = 0.f;
#pragma unroll
        for (int c = 0; c < 8; ++c) {
            uint32_t bx = (c >> 2) & 1, by = (c >> 1) & 1, bz = c & 1;
            uint32_t h = (ix + bx)
                       ^ ((iy + by) * 2654435761u)
                       ^ ((iz + bz) * 805459861u);
            uint32_t idx = base + (h & 0x7FFFFu);
            float w = (bx ? wx : 1.f - wx) * (by ? wy : 1.f - wy) * (bz ? wz : 1.f - wz);
            float2 v = unpack_bf16x2(tab[idx]);
            sx = fmaf(w, v.x, sx);
            sy = fmaf(w, v.y, sy);
        }
        *(float2*)(out + (size_t)p * 32 + 2 * l) = make_float2(sx, sy);
    }
}

// ------------------------------------------------- fused fallback (tiny ws)
__global__ __launch_bounds__(256) void fused_fallback_kernel(
    const float* __restrict__ xyz, const int* __restrict__ rays,
    const float* __restrict__ expw,
    const float2* __restrict__ mean, const float2* __restrict__ emb,
    float* __restrict__ out)
{
    int p = blockIdx.x * 256 + threadIdx.x;
    if (p >= NPOINTS) return;
    float x = xyz[3 * p], y = xyz[3 * p + 1], z = xyz[3 * p + 2];
    int frame = rays[p] >> 10;
    float e[8];
#pragma unroll
    for (int b = 0; b < 8; ++b) e[b] = expw[8 * frame + b];

    constexpr uint32_t OFFS[16] = OFFS_INIT;

    for (int l = 0; l < 16; ++l) {
        float scale = (float)((16 << l) - 1);
        float px = fmaf(x, scale, 0.5f);
        float py = fmaf(y, scale, 0.5f);
        float pz = fmaf(z, scale, 0.5f);
        float fx = floorf(px), fy = floorf(py), fz = floorf(pz);
        float wx = px - fx, wy = py - fy, wz = pz - fz;
        int ix = (int)fx, iy = (int)fy, iz = (int)fz;
        uint32_t base = OFFS[l];
        float sx = 0.f, sy = 0.f;
#pragma unroll
        for (int c = 0; c < 8; ++c) {
            int bx = (c >> 2) & 1, by = (c >> 1) & 1, bz = c & 1;
            uint32_t idx;
            if (l < 3) {
                uint32_t st = (l == 0) ? 17u : (l == 1) ? 33u : 65u;
                idx = (uint32_t)(ix + bx) + (uint32_t)(iy + by) * st
                    + (uint32_t)(iz + bz) * st * st;
            } else {
                idx = ((uint32_t)(ix + bx)
                     ^ ((uint32_t)(iy + by) * 2654435761u)
                     ^ ((uint32_t)(iz + bz) * 805459861u)) & 0x7FFFFu;
            }
            uint32_t g = base + idx;
            float2 m = mean[g];
            float vx = e[0] * m.x, vy = e[0] * m.y;
#pragma unroll
            for (int b = 0; b < 7; ++b) {
                float2 t = emb[(size_t)b * TOTAL_T + g];
                vx = fmaf(e[1 + b], t.x, vx);
                vy = fmaf(e[1 + b], t.y, vy);
            }
            float w = (bx ? wx : 1.f - wx) * (by ? wy : 1.f - wy) * (bz ? wz : 1.f - wz);
            sx = fmaf(w, vx, sx);
            sy = fmaf(w, vy, sy);
        }
        out[(size_t)p * 32 + 2 * l]     = sx;
        out[(size_t)p * 32 + 2 * l + 1] = sy;
    }
}

// ---------------------------------------------------------------- launch
extern "C" void kernel_launch(void* const* d_in, const int* in_sizes, int n_in,
                              void* d_out, int out_size, void* d_ws, size_t ws_size,
                              hipStream_t stream) {
    const float* inputs = (const float*)d_in[0];
    const float* expw   = (const float*)d_in[1];
    const float* mean   = (const float*)d_in[2];
    const float* emb    = (const float*)d_in[3];
    const int*   rays   = (const int*)d_in[4];
    float* out = (float*)d_out;

    const size_t need_bf16 = (size_t)4 * TPAD * 4;  // 114,100,224 B

    if (ws_size >= need_bf16) {
        uint32_t* cur = (uint32_t*)d_ws;
        const int blend_blocks = (int)((NG4 + 1 + 255) / 256);  // 6965
        blend_bf16x4_kernel<<<blend_blocks, 256, 0, stream>>>(
            (const float2*)mean, (const float2*)emb, expw, cur);
        gather_lvl_kernel<<<14 * 2048, 256, 0, stream>>>(
            inputs, rays, cur, out);
    } else {
        fused_fallback_kernel<<<NPOINTS / 256, 256, 0, stream>>>(
            inputs, rays, expw, (const float2*)mean, (const float2*)emb, out);
    }
}